// Round 8
// baseline (124.577 us; speedup 1.0000x reference)
//
#include <hip/hip_runtime.h>
#include <math.h>

// Problem constants (B, T, L, H) = (8, 32, 512, 768)
constexpr int Bn = 8, Tn = 32, Ln = 512, Hn = 768;

typedef __attribute__((ext_vector_type(8))) short bf16x8;   // 8 bf16 = 4 VGPRs
typedef __attribute__((ext_vector_type(4))) float f32x4;

__device__ __forceinline__ short f2bf(float x) {
    unsigned u = __float_as_uint(x);
    u += 0x7FFFu + ((u >> 16) & 1u);
    return (short)(u >> 16);
}
__device__ __forceinline__ float bf2f(unsigned short s) {
    return __uint_as_float(((unsigned)s) << 16);
}

// selu constants
constexpr float kScale = 1.0507009873554804934193349852946f;
constexpr float kAS    = 1.7580993408473768f;   // scale * alpha

__device__ __forceinline__ float selu(float x) {
    return x > 0.f ? kScale * x : fmaf(kAS, __expf(x), -kAS);
}

__device__ __forceinline__ bf16x8 pack8(float4 a, float4 b) {
    bf16x8 r;
    r[0] = f2bf(a.x); r[1] = f2bf(a.y); r[2] = f2bf(a.z); r[3] = f2bf(a.w);
    r[4] = f2bf(b.x); r[5] = f2bf(b.y); r[6] = f2bf(b.z); r[7] = f2bf(b.w);
    return r;
}

// ---------------------------------------------------------------------------
// Merged NT MFMA GEMM with FUSED fp32->bf16 conversion, both problems in one
// launch (unchanged from R7).
// ---------------------------------------------------------------------------
__global__ __launch_bounds__(256) void gemm2_f32_nt(
    const float* __restrict__ A1, const float* __restrict__ B1,
    unsigned short* __restrict__ C1, int M1,
    const float* __restrict__ A2, const float* __restrict__ B2,
    unsigned short* __restrict__ C2,
    int N, int K)
{
    constexpr int BM = 128, BN = 128, BK = 32;
    __shared__ __align__(16) short As[BM * BK];
    __shared__ __align__(16) short Bs[BN * BK];

    const int nblk1 = M1 / BM;
    const int bx = blockIdx.x;
    const float* A; const float* Bm; unsigned short* C; int bm;
    if (bx < nblk1) { A = A1; Bm = B1; C = C1; bm = bx * BM; }
    else            { A = A2; Bm = B2; C = C2; bm = (bx - nblk1) * BM; }
    const int bn = blockIdx.y * BN;

    const int tid  = threadIdx.x;
    const int lane = tid & 63;
    const int wv   = tid >> 6;          // 0..3
    const int quad = lane >> 4;         // 0..3
    const int l16  = lane & 15;
    const int wm   = (wv & 1) * 64;
    const int wn   = (wv >> 1) * 64;

    int srow[2], skk[2];
#pragma unroll
    for (int p = 0; p < 2; ++p) {
        const int unit = tid + (p << 8);
        srow[p] = unit >> 2;
        skk[p]  = (unit & 3) << 3;
    }

    f32x4 acc[4][4] = {};
    float4 cra[2][2], crb[2][2], nra[2][2], nrb[2][2];

    auto gload = [&](float4 ra[2][2], float4 rb[2][2], int k0) {
#pragma unroll
        for (int p = 0; p < 2; ++p) {
            const float* pa = A  + (size_t)(bm + srow[p]) * K + k0 + skk[p];
            ra[p][0] = *(const float4*)pa;
            ra[p][1] = *(const float4*)(pa + 4);
            const float* pb = Bm + (size_t)(bn + srow[p]) * K + k0 + skk[p];
            rb[p][0] = *(const float4*)pb;
            rb[p][1] = *(const float4*)(pb + 4);
        }
    };

    gload(cra, crb, 0);

    for (int k0 = 0; k0 < K; k0 += BK) {
        if (k0 + BK < K) gload(nra, nrb, k0 + BK);
        if (k0 > 0) __syncthreads();
#pragma unroll
        for (int p = 0; p < 2; ++p) {
            const int off = (tid + (p << 8)) << 3;
            *(bf16x8*)&As[off] = pack8(cra[p][0], cra[p][1]);
            *(bf16x8*)&Bs[off] = pack8(crb[p][0], crb[p][1]);
        }
        __syncthreads();

        bf16x8 af[4], bfr[4];
#pragma unroll
        for (int i = 0; i < 4; ++i)
            af[i] = *(const bf16x8*)&As[(wm + i * 16 + l16) * BK + quad * 8];
#pragma unroll
        for (int j = 0; j < 4; ++j)
            bfr[j] = *(const bf16x8*)&Bs[(wn + j * 16 + l16) * BK + quad * 8];
#pragma unroll
        for (int i = 0; i < 4; ++i)
#pragma unroll
            for (int j = 0; j < 4; ++j)
                acc[i][j] = __builtin_amdgcn_mfma_f32_16x16x32_bf16(af[i], bfr[j], acc[i][j], 0, 0, 0);

#pragma unroll
        for (int p = 0; p < 2; ++p) {
            cra[p][0] = nra[p][0]; cra[p][1] = nra[p][1];
            crb[p][0] = nrb[p][0]; crb[p][1] = nrb[p][1];
        }
    }

#pragma unroll
    for (int i = 0; i < 4; ++i)
#pragma unroll
        for (int j = 0; j < 4; ++j)
#pragma unroll
            for (int rr = 0; rr < 4; ++rr) {
                const int row = bm + wm + i * 16 + quad * 4 + rr;
                const int col = bn + wn + j * 16 + l16;
                C[(size_t)row * N + col] = (unsigned short)f2bf(acc[i][j][rr]);
            }
}

// ---------------------------------------------------------------------------
// Scores: sc[bt, l] = selu( sum_h selu(WE[b,l,h] + WD[bt,h]) * v[h] )
// Grid: 1024 blocks (bt x L-quarter) x 256 threads (4 waves) -> 4 blocks/CU,
// 16 waves/CU.  Quarters with no active rows retire instantly, so the
// cross-(b,t) mask-length imbalance is packed away (tail ~ avg, not max).
// Per row: one b128 load (h = 8*lane, [0,512)) + one b64 (h = 512+4*lane).
// Groups of 4 rows, interleaved across waves, 4 independent fma/shuffle
// chains.  b = bid&7 keeps WE[b] hot in one XCD's L2.
// ---------------------------------------------------------------------------
__global__ __launch_bounds__(256) void scores_kernel(
    const unsigned short* __restrict__ WE,  // [B*L, H] bf16
    const unsigned short* __restrict__ WD,  // [B*T, H] bf16
    const float* __restrict__ v,            // [H]
    const int* __restrict__ starts,         // [B*T]
    const int* __restrict__ lens,           // [B]
    float* __restrict__ sc)                 // [B*T, L]
{
    const int bid = blockIdx.x;
    const int b = bid & 7;
    const int r = bid >> 3;        // 0..127
    const int t = r & 31;
    const int q = r >> 5;          // 0..3  L-quarter
    const int bt = b * Tn + t;
    const int lane = threadIdx.x & 63;
    const int wv = threadIdx.x >> 6;        // 0..3

    const int start = starts[bt];
    const int len = lens[b];
    const int lbase = q * 128;
    // quarter fully masked? retire immediately
    if (lbase + 127 < start || lbase >= len) return;

    // Per-lane fragments: h8 = 8*lane (8 elems), h4 = 512 + 4*lane (4 elems)
    const int h8 = lane << 3;
    const int h4 = 512 + (lane << 2);
    float wd8[8], v8[8], wd4[4], v4[4];
    {
        const bf16x8 wdu8 = *(const bf16x8*)(WD + (size_t)bt * Hn + h8);
        const ushort4 wdu4 = *(const ushort4*)(WD + (size_t)bt * Hn + h4);
#pragma unroll
        for (int e = 0; e < 8; ++e) { wd8[e] = bf2f((unsigned short)wdu8[e]); v8[e] = v[h8 + e]; }
        wd4[0] = bf2f(wdu4.x); wd4[1] = bf2f(wdu4.y);
        wd4[2] = bf2f(wdu4.z); wd4[3] = bf2f(wdu4.w);
        const float4 vv = *(const float4*)(v + h4);
        v4[0] = vv.x; v4[1] = vv.y; v4[2] = vv.z; v4[3] = vv.w;
    }

    const unsigned short* WEb = WE + (size_t)b * Ln * Hn;

    for (int k = 0; k < 8; ++k) {
        const int g = wv + (k << 2);        // 0..31 within quarter
        const int lg = lbase + (g << 2);    // first l of this 4-row group
        if (lg + 3 < start || lg >= len) continue;   // fully masked -> skip

        // 8 loads up front (independent)
        bf16x8 w8[4]; ushort4 w4[4];
#pragma unroll
        for (int rr = 0; rr < 4; ++rr) {
            const unsigned short* row = WEb + (size_t)(lg + rr) * Hn;
            w8[rr] = *(const bf16x8*)(row + h8);
            w4[rr] = *(const ushort4*)(row + h4);
        }
        float s[4] = {0.f, 0.f, 0.f, 0.f};
#pragma unroll
        for (int e = 0; e < 8; ++e) {
#pragma unroll
            for (int rr = 0; rr < 4; ++rr) {   // 4 independent chains
                const float x = bf2f((unsigned short)w8[rr][e]) + wd8[e];
                s[rr] = fmaf(selu(x), v8[e], s[rr]);
            }
        }
        {
            const unsigned short c4[4][4] = {
                {w4[0].x, w4[0].y, w4[0].z, w4[0].w},
                {w4[1].x, w4[1].y, w4[1].z, w4[1].w},
                {w4[2].x, w4[2].y, w4[2].z, w4[2].w},
                {w4[3].x, w4[3].y, w4[3].z, w4[3].w}};
#pragma unroll
            for (int e = 0; e < 4; ++e)
#pragma unroll
                for (int rr = 0; rr < 4; ++rr) {
                    const float x = bf2f(c4[rr][e]) + wd4[e];
                    s[rr] = fmaf(selu(x), v4[e], s[rr]);
                }
        }
        // 4 interleaved shuffle-reduce trees
#pragma unroll
        for (int off = 32; off > 0; off >>= 1) {
#pragma unroll
            for (int rr = 0; rr < 4; ++rr)
                s[rr] += __shfl_xor(s[rr], off, 64);
        }
        if (lane == 0) {
#pragma unroll
            for (int rr = 0; rr < 4; ++rr)
                sc[(size_t)bt * Ln + lg + rr] = selu(s[rr]);
        }
    }
}

// ---------------------------------------------------------------------------
// Masked log-softmax over L=512. One block per bt, 512 threads.
// ---------------------------------------------------------------------------
__global__ __launch_bounds__(512) void softmax_kernel(
    const float* __restrict__ sc,     // [B*T, L]
    const int* __restrict__ starts,   // [B*T]
    const int* __restrict__ lens,     // [B]
    float* __restrict__ out)          // [B*T, L]
{
    __shared__ float red[16];
    const int bt = blockIdx.x;
    const int b = bt / Tn;
    const int tid = threadIdx.x;
    const int lane = tid & 63;
    const int wv = tid >> 6;

    const int start = starts[bt];
    const int len = lens[b];
    const int l = tid;
    const bool msk = (l >= start) && (l < len);
    const float val = msk ? sc[(size_t)bt * Ln + l] : -1e30f;

    float mx = val;
#pragma unroll
    for (int off = 32; off > 0; off >>= 1)
        mx = fmaxf(mx, __shfl_xor(mx, off, 64));
    if (lane == 0) red[wv] = mx;
    __syncthreads();
    mx = red[0];
#pragma unroll
    for (int i = 1; i < 8; ++i) mx = fmaxf(mx, red[i]);

    float sm = msk ? __expf(val - mx) : 0.f;
#pragma unroll
    for (int off = 32; off > 0; off >>= 1)
        sm += __shfl_xor(sm, off, 64);
    if (lane == 0) red[8 + wv] = sm;
    __syncthreads();
    float tot = red[8];
#pragma unroll
    for (int i = 1; i < 8; ++i) tot += red[8 + i];

    const float logZ = mx + __logf(tot);
    out[(size_t)bt * Ln + l] = msk ? (val - logZ) : 0.f;
}

// ---------------------------------------------------------------------------
extern "C" void kernel_launch(void* const* d_in, const int* in_sizes, int n_in,
                              void* d_out, int out_size, void* d_ws, size_t ws_size,
                              hipStream_t stream) {
    const float* enc    = (const float*)d_in[0];  // [B, L, H]
    const float* dec    = (const float*)d_in[1];  // [B, T, H]
    const float* W1     = (const float*)d_in[2];  // [H, H]
    const float* W2     = (const float*)d_in[3];  // [H, H]
    const float* v      = (const float*)d_in[4];  // [H]
    const int*   starts = (const int*)d_in[5];    // [B, T]
    const int*   lens   = (const int*)d_in[6];    // [B]
    float* out = (float*)d_out;

    constexpr int n_enc = Bn * Ln * Hn;   // 3,145,728
    constexpr int n_dec = Bn * Tn * Hn;   //   196,608
    constexpr int n_sc  = Bn * Tn * Ln;   //   131,072

    const size_t need = (size_t)(n_enc + n_dec) * 2 + (size_t)n_sc * 4;
    if (ws_size < need) return;  // visible failure

    unsigned short* WE16 = (unsigned short*)d_ws;
    unsigned short* WD16 = WE16 + n_enc;
    float* sc = (float*)(WD16 + n_dec);

    // Both GEMMs (fused fp32->bf16 input conversion) in one launch.
    gemm2_f32_nt<<<dim3((Bn * Ln) / 128 + (Bn * Tn) / 128, Hn / 128),
                   dim3(256), 0, stream>>>(
        enc, W1, WE16, Bn * Ln,
        dec, W2, WD16, Hn, Hn);

    scores_kernel<<<dim3(1024), dim3(256), 0, stream>>>(
        WE16, WD16, v, starts, lens, sc);
    softmax_kernel<<<dim3(Bn * Tn), dim3(512), 0, stream>>>(
        sc, starts, lens, out);
}

// Round 9
// 123.933 us; speedup vs baseline: 1.0052x; 1.0052x over previous
//
#include <hip/hip_runtime.h>
#include <math.h>

// Problem constants (B, T, L, H) = (8, 32, 512, 768)
constexpr int Bn = 8, Tn = 32, Ln = 512, Hn = 768;

typedef __attribute__((ext_vector_type(8))) short bf16x8;   // 8 bf16 = 4 VGPRs
typedef __attribute__((ext_vector_type(4))) float f32x4;

__device__ __forceinline__ short f2bf(float x) {
    unsigned u = __float_as_uint(x);
    u += 0x7FFFu + ((u >> 16) & 1u);
    return (short)(u >> 16);
}
__device__ __forceinline__ float bf2f(unsigned short s) {
    return __uint_as_float(((unsigned)s) << 16);
}

// selu constants
constexpr float kScale = 1.0507009873554804934193349852946f;
constexpr float kAS    = 1.7580993408473768f;   // scale * alpha

__device__ __forceinline__ float selu(float x) {
    return x > 0.f ? kScale * x : fmaf(kAS, __expf(x), -kAS);
}

__device__ __forceinline__ bf16x8 pack8(float4 a, float4 b) {
    bf16x8 r;
    r[0] = f2bf(a.x); r[1] = f2bf(a.y); r[2] = f2bf(a.z); r[3] = f2bf(a.w);
    r[4] = f2bf(b.x); r[5] = f2bf(b.y); r[6] = f2bf(b.z); r[7] = f2bf(b.w);
    return r;
}

// ---------------------------------------------------------------------------
// Merged NT MFMA GEMM with FUSED fp32->bf16 conversion, both problems in one
// launch (unchanged from R7: 122.0 µs best).
// ---------------------------------------------------------------------------
__global__ __launch_bounds__(256) void gemm2_f32_nt(
    const float* __restrict__ A1, const float* __restrict__ B1,
    unsigned short* __restrict__ C1, int M1,
    const float* __restrict__ A2, const float* __restrict__ B2,
    unsigned short* __restrict__ C2,
    int N, int K)
{
    constexpr int BM = 128, BN = 128, BK = 32;
    __shared__ __align__(16) short As[BM * BK];
    __shared__ __align__(16) short Bs[BN * BK];

    const int nblk1 = M1 / BM;
    const int bx = blockIdx.x;
    const float* A; const float* Bm; unsigned short* C; int bm;
    if (bx < nblk1) { A = A1; Bm = B1; C = C1; bm = bx * BM; }
    else            { A = A2; Bm = B2; C = C2; bm = (bx - nblk1) * BM; }
    const int bn = blockIdx.y * BN;

    const int tid  = threadIdx.x;
    const int lane = tid & 63;
    const int wv   = tid >> 6;          // 0..3
    const int quad = lane >> 4;         // 0..3
    const int l16  = lane & 15;
    const int wm   = (wv & 1) * 64;
    const int wn   = (wv >> 1) * 64;

    int srow[2], skk[2];
#pragma unroll
    for (int p = 0; p < 2; ++p) {
        const int unit = tid + (p << 8);
        srow[p] = unit >> 2;
        skk[p]  = (unit & 3) << 3;
    }

    f32x4 acc[4][4] = {};
    float4 cra[2][2], crb[2][2], nra[2][2], nrb[2][2];

    auto gload = [&](float4 ra[2][2], float4 rb[2][2], int k0) {
#pragma unroll
        for (int p = 0; p < 2; ++p) {
            const float* pa = A  + (size_t)(bm + srow[p]) * K + k0 + skk[p];
            ra[p][0] = *(const float4*)pa;
            ra[p][1] = *(const float4*)(pa + 4);
            const float* pb = Bm + (size_t)(bn + srow[p]) * K + k0 + skk[p];
            rb[p][0] = *(const float4*)pb;
            rb[p][1] = *(const float4*)(pb + 4);
        }
    };

    gload(cra, crb, 0);

    for (int k0 = 0; k0 < K; k0 += BK) {
        if (k0 + BK < K) gload(nra, nrb, k0 + BK);
        if (k0 > 0) __syncthreads();
#pragma unroll
        for (int p = 0; p < 2; ++p) {
            const int off = (tid + (p << 8)) << 3;
            *(bf16x8*)&As[off] = pack8(cra[p][0], cra[p][1]);
            *(bf16x8*)&Bs[off] = pack8(crb[p][0], crb[p][1]);
        }
        __syncthreads();

        bf16x8 af[4], bfr[4];
#pragma unroll
        for (int i = 0; i < 4; ++i)
            af[i] = *(const bf16x8*)&As[(wm + i * 16 + l16) * BK + quad * 8];
#pragma unroll
        for (int j = 0; j < 4; ++j)
            bfr[j] = *(const bf16x8*)&Bs[(wn + j * 16 + l16) * BK + quad * 8];
#pragma unroll
        for (int i = 0; i < 4; ++i)
#pragma unroll
            for (int j = 0; j < 4; ++j)
                acc[i][j] = __builtin_amdgcn_mfma_f32_16x16x32_bf16(af[i], bfr[j], acc[i][j], 0, 0, 0);

#pragma unroll
        for (int p = 0; p < 2; ++p) {
            cra[p][0] = nra[p][0]; cra[p][1] = nra[p][1];
            crb[p][0] = nrb[p][0]; crb[p][1] = nrb[p][1];
        }
    }

#pragma unroll
    for (int i = 0; i < 4; ++i)
#pragma unroll
        for (int j = 0; j < 4; ++j)
#pragma unroll
            for (int rr = 0; rr < 4; ++rr) {
                const int row = bm + wm + i * 16 + quad * 4 + rr;
                const int col = bn + wn + j * 16 + l16;
                C[(size_t)row * N + col] = (unsigned short)f2bf(acc[i][j][rr]);
            }
}

// ---------------------------------------------------------------------------
// Fused scores + masked log-softmax.  One block per (b,t): 1024 threads =
// 16 waves.  Each wave's active 4-row groups (g = wv + 16k) form a
// CONTIGUOUS k-range [k_lo,k_hi] (mask region is one interval) -> no
// divergent skips; groups are SOFTWARE-PIPELINED: group k+1's 8 WE loads
// (1x b128 + 1x b64 per row) are issued before computing group k, so the
// ~430-instr compute phase hides the L2 latency.  4 independent fma/shuffle
// chains per group.  Softmax phase: first 512 threads, one per l.
// b = bid&7 keeps WE[b] (786 KB bf16) hot in one XCD's L2.
// ---------------------------------------------------------------------------
__global__ __launch_bounds__(1024) void scores_softmax_fused(
    const unsigned short* __restrict__ WE,  // [B*L, H] bf16
    const unsigned short* __restrict__ WD,  // [B*T, H] bf16
    const float* __restrict__ v,            // [H]
    const int* __restrict__ starts,         // [B*T]
    const int* __restrict__ lens,           // [B]
    float* __restrict__ out)                // [B*T, L]
{
    const int bid = blockIdx.x;
    const int b = bid & 7;
    const int t = bid >> 3;
    const int bt = b * Tn + t;
    const int tid = threadIdx.x;
    const int lane = tid & 63;
    const int wv = tid >> 6;            // 0..15

    __shared__ float sc[Ln];
    __shared__ float red[16];

    const int start = starts[bt];
    const int len = lens[b];

    // Per-lane fragments: h8 = 8*lane (8 elems), h4 = 512 + 4*lane (4 elems)
    const int h8 = lane << 3;
    const int h4 = 512 + (lane << 2);
    float wd8[8], v8[8], wd4[4], v4[4];
    {
        const bf16x8 wdu8 = *(const bf16x8*)(WD + (size_t)bt * Hn + h8);
        const ushort4 wdu4 = *(const ushort4*)(WD + (size_t)bt * Hn + h4);
        const float4 vv0 = *(const float4*)(v + h8);
        const float4 vv1 = *(const float4*)(v + h8 + 4);
        const float4 vv2 = *(const float4*)(v + h4);
#pragma unroll
        for (int e = 0; e < 8; ++e) wd8[e] = bf2f((unsigned short)wdu8[e]);
        v8[0] = vv0.x; v8[1] = vv0.y; v8[2] = vv0.z; v8[3] = vv0.w;
        v8[4] = vv1.x; v8[5] = vv1.y; v8[6] = vv1.z; v8[7] = vv1.w;
        wd4[0] = bf2f(wdu4.x); wd4[1] = bf2f(wdu4.y);
        wd4[2] = bf2f(wdu4.z); wd4[3] = bf2f(wdu4.w);
        v4[0] = vv2.x; v4[1] = vv2.y; v4[2] = vv2.z; v4[3] = vv2.w;
    }

    const unsigned short* WEb = WE + (size_t)b * Ln * Hn;

    // Active group range (global): g in [g_lo, g_hi]
    const int g_lo = start >> 2;          // ceil((start-3)/4)
    const int g_hi = (len - 1) >> 2;
    // This wave's k-range: g = wv + 16k
    const int k_lo = (g_lo > wv) ? (g_lo - wv + 15) >> 4 : 0;
    const int k_hi = (g_hi >= wv) ? (g_hi - wv) >> 4 : -1;

    bf16x8 cw8[4], nw8[4]; ushort4 cw4[4], nw4[4];

    auto loadg = [&](bf16x8 w8[4], ushort4 w4[4], int k) {
        const int lg = (wv + (k << 4)) << 2;
#pragma unroll
        for (int rr = 0; rr < 4; ++rr) {
            const unsigned short* row = WEb + (size_t)(lg + rr) * Hn;
            w8[rr] = *(const bf16x8*)(row + h8);
            w4[rr] = *(const ushort4*)(row + h4);
        }
    };

    if (k_lo <= k_hi) loadg(cw8, cw4, k_lo);

    for (int k = k_lo; k <= k_hi; ++k) {
        if (k < k_hi) loadg(nw8, nw4, k + 1);   // prefetch next group

        float s[4] = {0.f, 0.f, 0.f, 0.f};
#pragma unroll
        for (int e = 0; e < 8; ++e) {
#pragma unroll
            for (int rr = 0; rr < 4; ++rr) {    // 4 independent chains
                const float x = bf2f((unsigned short)cw8[rr][e]) + wd8[e];
                s[rr] = fmaf(selu(x), v8[e], s[rr]);
            }
        }
        {
            const unsigned short c4[4][4] = {
                {cw4[0].x, cw4[0].y, cw4[0].z, cw4[0].w},
                {cw4[1].x, cw4[1].y, cw4[1].z, cw4[1].w},
                {cw4[2].x, cw4[2].y, cw4[2].z, cw4[2].w},
                {cw4[3].x, cw4[3].y, cw4[3].z, cw4[3].w}};
#pragma unroll
            for (int e = 0; e < 4; ++e)
#pragma unroll
                for (int rr = 0; rr < 4; ++rr) {
                    const float x = bf2f(c4[rr][e]) + wd4[e];
                    s[rr] = fmaf(selu(x), v4[e], s[rr]);
                }
        }
        // 4 interleaved shuffle-reduce trees
#pragma unroll
        for (int off = 32; off > 0; off >>= 1) {
#pragma unroll
            for (int rr = 0; rr < 4; ++rr)
                s[rr] += __shfl_xor(s[rr], off, 64);
        }
        if (lane == 0) {
            const int lg = (wv + (k << 4)) << 2;
#pragma unroll
            for (int rr = 0; rr < 4; ++rr)
                sc[lg + rr] = selu(s[rr]);
        }
        // rotate prefetch buffers
#pragma unroll
        for (int rr = 0; rr < 4; ++rr) { cw8[rr] = nw8[rr]; cw4[rr] = nw4[rr]; }
    }
    __syncthreads();

    // ---- masked log-softmax over L (threads 0..511, one per l) ----
    const int l = tid;
    const bool active = (l < Ln);
    const bool msk = active && (l >= start) && (l < len);
    const float val = msk ? sc[l] : -1e30f;

    float mx = val;
#pragma unroll
    for (int off = 32; off > 0; off >>= 1)
        mx = fmaxf(mx, __shfl_xor(mx, off, 64));
    if (lane == 0 && wv < 8) red[wv] = mx;
    __syncthreads();
    mx = red[0];
#pragma unroll
    for (int i = 1; i < 8; ++i) mx = fmaxf(mx, red[i]);

    float sm = msk ? __expf(val - mx) : 0.f;
#pragma unroll
    for (int off = 32; off > 0; off >>= 1)
        sm += __shfl_xor(sm, off, 64);
    if (lane == 0 && wv < 8) red[8 + wv] = sm;
    __syncthreads();
    float tot = red[8];
#pragma unroll
    for (int i = 1; i < 8; ++i) tot += red[8 + i];

    if (active) {
        const float logZ = mx + __logf(tot);
        out[(size_t)bt * Ln + l] = msk ? (val - logZ) : 0.f;
    }
}

// ---------------------------------------------------------------------------
extern "C" void kernel_launch(void* const* d_in, const int* in_sizes, int n_in,
                              void* d_out, int out_size, void* d_ws, size_t ws_size,
                              hipStream_t stream) {
    const float* enc    = (const float*)d_in[0];  // [B, L, H]
    const float* dec    = (const float*)d_in[1];  // [B, T, H]
    const float* W1     = (const float*)d_in[2];  // [H, H]
    const float* W2     = (const float*)d_in[3];  // [H, H]
    const float* v      = (const float*)d_in[4];  // [H]
    const int*   starts = (const int*)d_in[5];    // [B, T]
    const int*   lens   = (const int*)d_in[6];    // [B]
    float* out = (float*)d_out;

    constexpr int n_enc = Bn * Ln * Hn;   // 3,145,728
    constexpr int n_dec = Bn * Tn * Hn;   //   196,608

    const size_t need = (size_t)(n_enc + n_dec) * 2;   // WE16 + WD16
    if (ws_size < need) return;  // visible failure

    unsigned short* WE16 = (unsigned short*)d_ws;
    unsigned short* WD16 = WE16 + n_enc;

    // Both GEMMs (fused fp32->bf16 input conversion) in one launch.
    gemm2_f32_nt<<<dim3((Bn * Ln) / 128 + (Bn * Tn) / 128, Hn / 128),
                   dim3(256), 0, stream>>>(
        enc, W1, WE16, Bn * Ln,
        dec, W2, WD16, Hn, Hn);

    scores_softmax_fused<<<dim3(Bn * Tn), dim3(1024), 0, stream>>>(
        WE16, WD16, v, starts, lens, out);
}

// Round 10
// 121.106 us; speedup vs baseline: 1.0287x; 1.0233x over previous
//
#include <hip/hip_runtime.h>
#include <math.h>

// Problem constants (B, T, L, H) = (8, 32, 512, 768)
constexpr int Bn = 8, Tn = 32, Ln = 512, Hn = 768;

typedef __attribute__((ext_vector_type(8))) short bf16x8;   // 8 bf16 = 4 VGPRs
typedef __attribute__((ext_vector_type(4))) float f32x4;

__device__ __forceinline__ short f2bf(float x) {
    unsigned u = __float_as_uint(x);
    u += 0x7FFFu + ((u >> 16) & 1u);
    return (short)(u >> 16);
}
__device__ __forceinline__ float bf2f(unsigned short s) {
    return __uint_as_float(((unsigned)s) << 16);
}

// selu constants
constexpr float kScale = 1.0507009873554804934193349852946f;
constexpr float kAS    = 1.7580993408473768f;   // scale * alpha

__device__ __forceinline__ float selu(float x) {
    return x > 0.f ? kScale * x : fmaf(kAS, __expf(x), -kAS);
}

__device__ __forceinline__ bf16x8 pack8(float4 a, float4 b) {
    bf16x8 r;
    r[0] = f2bf(a.x); r[1] = f2bf(a.y); r[2] = f2bf(a.z); r[3] = f2bf(a.w);
    r[4] = f2bf(b.x); r[5] = f2bf(b.y); r[6] = f2bf(b.z); r[7] = f2bf(b.w);
    return r;
}

// ---------------------------------------------------------------------------
// Merged NT MFMA GEMM with FUSED fp32->bf16 conversion, both problems in one
// launch (unchanged from R7: 122.0 µs best).
// ---------------------------------------------------------------------------
__global__ __launch_bounds__(256) void gemm2_f32_nt(
    const float* __restrict__ A1, const float* __restrict__ B1,
    unsigned short* __restrict__ C1, int M1,
    const float* __restrict__ A2, const float* __restrict__ B2,
    unsigned short* __restrict__ C2,
    int N, int K)
{
    constexpr int BM = 128, BN = 128, BK = 32;
    __shared__ __align__(16) short As[BM * BK];
    __shared__ __align__(16) short Bs[BN * BK];

    const int nblk1 = M1 / BM;
    const int bx = blockIdx.x;
    const float* A; const float* Bm; unsigned short* C; int bm;
    if (bx < nblk1) { A = A1; Bm = B1; C = C1; bm = bx * BM; }
    else            { A = A2; Bm = B2; C = C2; bm = (bx - nblk1) * BM; }
    const int bn = blockIdx.y * BN;

    const int tid  = threadIdx.x;
    const int lane = tid & 63;
    const int wv   = tid >> 6;          // 0..3
    const int quad = lane >> 4;         // 0..3
    const int l16  = lane & 15;
    const int wm   = (wv & 1) * 64;
    const int wn   = (wv >> 1) * 64;

    int srow[2], skk[2];
#pragma unroll
    for (int p = 0; p < 2; ++p) {
        const int unit = tid + (p << 8);
        srow[p] = unit >> 2;
        skk[p]  = (unit & 3) << 3;
    }

    f32x4 acc[4][4] = {};
    float4 cra[2][2], crb[2][2], nra[2][2], nrb[2][2];

    auto gload = [&](float4 ra[2][2], float4 rb[2][2], int k0) {
#pragma unroll
        for (int p = 0; p < 2; ++p) {
            const float* pa = A  + (size_t)(bm + srow[p]) * K + k0 + skk[p];
            ra[p][0] = *(const float4*)pa;
            ra[p][1] = *(const float4*)(pa + 4);
            const float* pb = Bm + (size_t)(bn + srow[p]) * K + k0 + skk[p];
            rb[p][0] = *(const float4*)pb;
            rb[p][1] = *(const float4*)(pb + 4);
        }
    };

    gload(cra, crb, 0);

    for (int k0 = 0; k0 < K; k0 += BK) {
        if (k0 + BK < K) gload(nra, nrb, k0 + BK);
        if (k0 > 0) __syncthreads();
#pragma unroll
        for (int p = 0; p < 2; ++p) {
            const int off = (tid + (p << 8)) << 3;
            *(bf16x8*)&As[off] = pack8(cra[p][0], cra[p][1]);
            *(bf16x8*)&Bs[off] = pack8(crb[p][0], crb[p][1]);
        }
        __syncthreads();

        bf16x8 af[4], bfr[4];
#pragma unroll
        for (int i = 0; i < 4; ++i)
            af[i] = *(const bf16x8*)&As[(wm + i * 16 + l16) * BK + quad * 8];
#pragma unroll
        for (int j = 0; j < 4; ++j)
            bfr[j] = *(const bf16x8*)&Bs[(wn + j * 16 + l16) * BK + quad * 8];
#pragma unroll
        for (int i = 0; i < 4; ++i)
#pragma unroll
            for (int j = 0; j < 4; ++j)
                acc[i][j] = __builtin_amdgcn_mfma_f32_16x16x32_bf16(af[i], bfr[j], acc[i][j], 0, 0, 0);

#pragma unroll
        for (int p = 0; p < 2; ++p) {
            cra[p][0] = nra[p][0]; cra[p][1] = nra[p][1];
            crb[p][0] = nrb[p][0]; crb[p][1] = nrb[p][1];
        }
    }

#pragma unroll
    for (int i = 0; i < 4; ++i)
#pragma unroll
        for (int j = 0; j < 4; ++j)
#pragma unroll
            for (int rr = 0; rr < 4; ++rr) {
                const int row = bm + wm + i * 16 + quad * 4 + rr;
                const int col = bn + wn + j * 16 + l16;
                C[(size_t)row * N + col] = (unsigned short)f2bf(acc[i][j][rr]);
            }
}

// ---------------------------------------------------------------------------
// Fused scores + masked log-softmax (R7 structure, R8's 8-load layout).
// One block per (b,t): 1024 threads = 16 waves.  Groups of 4 l-rows
// interleaved across waves (g = wv + 16k); fully-masked groups skipped.
// Per row: one b128 load (h = 8*lane, [0,512)) + one b64 (h = 512+4*lane).
// 4 independent fma/shuffle chains per group.  No register double-buffering
// (keeps VGPR < 128 so 4 waves/SIMD are sustained — R9's prefetch regressed
// via this cliff).  Softmax phase: first 512 threads, one per l.
// b = bid&7 keeps WE[b] (786 KB bf16) hot in one XCD's L2.
// ---------------------------------------------------------------------------
__global__ __launch_bounds__(1024) void scores_softmax_fused(
    const unsigned short* __restrict__ WE,  // [B*L, H] bf16
    const unsigned short* __restrict__ WD,  // [B*T, H] bf16
    const float* __restrict__ v,            // [H]
    const int* __restrict__ starts,         // [B*T]
    const int* __restrict__ lens,           // [B]
    float* __restrict__ out)                // [B*T, L]
{
    const int bid = blockIdx.x;
    const int b = bid & 7;
    const int t = bid >> 3;
    const int bt = b * Tn + t;
    const int tid = threadIdx.x;
    const int lane = tid & 63;
    const int wv = tid >> 6;            // 0..15

    __shared__ float sc[Ln];
    __shared__ float red[16];

    const int start = starts[bt];
    const int len = lens[b];

    // Per-lane fragments: h8 = 8*lane (8 elems), h4 = 512 + 4*lane (4 elems)
    const int h8 = lane << 3;
    const int h4 = 512 + (lane << 2);
    float wd8[8], v8[8], wd4[4], v4[4];
    {
        const bf16x8 wdu8 = *(const bf16x8*)(WD + (size_t)bt * Hn + h8);
        const ushort4 wdu4 = *(const ushort4*)(WD + (size_t)bt * Hn + h4);
        const float4 vv0 = *(const float4*)(v + h8);
        const float4 vv1 = *(const float4*)(v + h8 + 4);
        const float4 vv2 = *(const float4*)(v + h4);
#pragma unroll
        for (int e = 0; e < 8; ++e) wd8[e] = bf2f((unsigned short)wdu8[e]);
        v8[0] = vv0.x; v8[1] = vv0.y; v8[2] = vv0.z; v8[3] = vv0.w;
        v8[4] = vv1.x; v8[5] = vv1.y; v8[6] = vv1.z; v8[7] = vv1.w;
        wd4[0] = bf2f(wdu4.x); wd4[1] = bf2f(wdu4.y);
        wd4[2] = bf2f(wdu4.z); wd4[3] = bf2f(wdu4.w);
        v4[0] = vv2.x; v4[1] = vv2.y; v4[2] = vv2.z; v4[3] = vv2.w;
    }

    const unsigned short* WEb = WE + (size_t)b * Ln * Hn;

    for (int k = 0; k < 8; ++k) {
        const int g = wv + (k << 4);    // interleaved group id, 0..127
        const int lg = g << 2;          // first l of this 4-row group
        if (lg + 3 < start || lg >= len) continue;   // fully masked -> skip

        // 8 loads up front (independent)
        bf16x8 w8[4]; ushort4 w4[4];
#pragma unroll
        for (int rr = 0; rr < 4; ++rr) {
            const unsigned short* row = WEb + (size_t)(lg + rr) * Hn;
            w8[rr] = *(const bf16x8*)(row + h8);
            w4[rr] = *(const ushort4*)(row + h4);
        }
        float s[4] = {0.f, 0.f, 0.f, 0.f};
#pragma unroll
        for (int e = 0; e < 8; ++e) {
#pragma unroll
            for (int rr = 0; rr < 4; ++rr) {    // 4 independent chains
                const float x = bf2f((unsigned short)w8[rr][e]) + wd8[e];
                s[rr] = fmaf(selu(x), v8[e], s[rr]);
            }
        }
        {
            const unsigned short c4[4][4] = {
                {w4[0].x, w4[0].y, w4[0].z, w4[0].w},
                {w4[1].x, w4[1].y, w4[1].z, w4[1].w},
                {w4[2].x, w4[2].y, w4[2].z, w4[2].w},
                {w4[3].x, w4[3].y, w4[3].z, w4[3].w}};
#pragma unroll
            for (int e = 0; e < 4; ++e)
#pragma unroll
                for (int rr = 0; rr < 4; ++rr) {
                    const float x = bf2f(c4[rr][e]) + wd4[e];
                    s[rr] = fmaf(selu(x), v4[e], s[rr]);
                }
        }
        // 4 interleaved shuffle-reduce trees
#pragma unroll
        for (int off = 32; off > 0; off >>= 1) {
#pragma unroll
            for (int rr = 0; rr < 4; ++rr)
                s[rr] += __shfl_xor(s[rr], off, 64);
        }
        if (lane == 0) {
#pragma unroll
            for (int rr = 0; rr < 4; ++rr)
                sc[lg + rr] = selu(s[rr]);
        }
    }
    __syncthreads();

    // ---- masked log-softmax over L (threads 0..511, one per l) ----
    const int l = tid;
    const bool active = (l < Ln);
    const bool msk = active && (l >= start) && (l < len);
    const float val = msk ? sc[l] : -1e30f;

    float mx = val;
#pragma unroll
    for (int off = 32; off > 0; off >>= 1)
        mx = fmaxf(mx, __shfl_xor(mx, off, 64));
    if (lane == 0 && wv < 8) red[wv] = mx;
    __syncthreads();
    mx = red[0];
#pragma unroll
    for (int i = 1; i < 8; ++i) mx = fmaxf(mx, red[i]);

    float sm = msk ? __expf(val - mx) : 0.f;
#pragma unroll
    for (int off = 32; off > 0; off >>= 1)
        sm += __shfl_xor(sm, off, 64);
    if (lane == 0 && wv < 8) red[8 + wv] = sm;
    __syncthreads();
    float tot = red[8];
#pragma unroll
    for (int i = 1; i < 8; ++i) tot += red[8 + i];

    if (active) {
        const float logZ = mx + __logf(tot);
        out[(size_t)bt * Ln + l] = msk ? (val - logZ) : 0.f;
    }
}

// ---------------------------------------------------------------------------
extern "C" void kernel_launch(void* const* d_in, const int* in_sizes, int n_in,
                              void* d_out, int out_size, void* d_ws, size_t ws_size,
                              hipStream_t stream) {
    const float* enc    = (const float*)d_in[0];  // [B, L, H]
    const float* dec    = (const float*)d_in[1];  // [B, T, H]
    const float* W1     = (const float*)d_in[2];  // [H, H]
    const float* W2     = (const float*)d_in[3];  // [H, H]
    const float* v      = (const float*)d_in[4];  // [H]
    const int*   starts = (const int*)d_in[5];    // [B, T]
    const int*   lens   = (const int*)d_in[6];    // [B]
    float* out = (float*)d_out;

    constexpr int n_enc = Bn * Ln * Hn;   // 3,145,728
    constexpr int n_dec = Bn * Tn * Hn;   //   196,608

    const size_t need = (size_t)(n_enc + n_dec) * 2;   // WE16 + WD16
    if (ws_size < need) return;  // visible failure

    unsigned short* WE16 = (unsigned short*)d_ws;
    unsigned short* WD16 = WE16 + n_enc;

    // Both GEMMs (fused fp32->bf16 input conversion) in one launch.
    gemm2_f32_nt<<<dim3((Bn * Ln) / 128 + (Bn * Tn) / 128, Hn / 128),
                   dim3(256), 0, stream>>>(
        enc, W1, WE16, Bn * Ln,
        dec, W2, WD16, Hn, Hn);

    scores_softmax_fused<<<dim3(Bn * Tn), dim3(1024), 0, stream>>>(
        WE16, WD16, v, starts, lens, out);
}